// Round 1
// baseline (481.439 us; speedup 1.0000x reference)
//
#include <hip/hip_runtime.h>
#include <cstdint>
#include <cstddef>

#define BB 16
#define NN 8192
#define DD 384
#define HH 128
#define KK 8
#define DEG 16

// 8 bf16 (as shorts, 4 VGPRs) per guide §3; f32x4 accumulator
typedef short bf8_t __attribute__((ext_vector_type(8)));
typedef float f4_t __attribute__((ext_vector_type(4)));

__device__ __forceinline__ unsigned short f2bf(float f) {
  unsigned int u = __float_as_uint(f);
  u += 0x7FFFu + ((u >> 16) & 1u);   // RNE
  return (unsigned short)(u >> 16);
}

// ---------------------------------------------------------------------------
// Kprep: fold q@W[384:,:]+bias into per-batch base vectors; transpose+convert
// W1[:384]/P1[:384] to bf16 [H][D] layout; zero normsq accumulators.
// ---------------------------------------------------------------------------
__global__ __launch_bounds__(256) void kprep(
    const float* __restrict__ q, const float* __restrict__ W1,
    const float* __restrict__ b1, const float* __restrict__ P1,
    const float* __restrict__ pb1,
    unsigned short* __restrict__ W1t, unsigned short* __restrict__ P1t,
    float* __restrict__ base1, float* __restrict__ baseP,
    float* __restrict__ normsq)
{
  int blk = blockIdx.x, t = threadIdx.x;
  if (blk < BB) {
    int net = t >> 7, h = t & 127;
    const float* W = net ? P1 : W1;
    float acc = net ? pb1[h] : b1[h];
    const float* qb = q + blk * DD;
    for (int d = 0; d < DD; ++d)
      acc = fmaf(qb[d], W[(DD + d) * HH + h], acc);
    (net ? baseP : base1)[blk * HH + h] = acc;
  } else {
    int e = (blk - BB) * 3072 + t;   // 32 blocks x 3072 = 2*49152 elems
    for (int it = 0; it < 12; ++it, e += 256) {
      int net = e / 49152;
      int r = e - net * 49152;
      int d = r >> 7;                // 0..383 (contiguous reads)
      int h = r & 127;
      float v = (net ? P1 : W1)[d * HH + h];
      (net ? P1t : W1t)[h * DD + d] = f2bf(v);
    }
    if (blk == BB && t < BB) normsq[t] = 0.f;
  }
}

// ---------------------------------------------------------------------------
// Kmlp: fused bf16-MFMA GEMM (emb[64xK384] x {W1t,P1t}[K384x128]) + relu +
// second matmuls (W2 -> 8 amps, P2 -> path scalar) + sigmoid/label scaling.
// Block = 64 rows x 128 cols x 2 nets; 4 waves, wave w owns rows w*16..+15.
// ---------------------------------------------------------------------------
__global__ __launch_bounds__(256) void kmlp(
    const float* __restrict__ emb, const int* __restrict__ labels,
    const unsigned short* __restrict__ W1t, const unsigned short* __restrict__ P1t,
    const float* __restrict__ base1, const float* __restrict__ baseP,
    const float* __restrict__ W2, const float* __restrict__ b2,
    const float* __restrict__ P2, const float* __restrict__ pb2,
    float* __restrict__ amps)
{
  // rows padded to 40 shorts (80 B): 20-bank offset per row -> ~2-way (free)
  __shared__ __align__(16) unsigned short sA[64 * 40];
  __shared__ __align__(16) unsigned short sB1[128 * 40];
  __shared__ __align__(16) unsigned short sBP[128 * 40];
  __shared__ float sBase1[128], sBaseP[128], sW2t[8 * 128], sP2[128], sB2[8];

  const int t = threadIdx.x;
  const int b = blockIdx.x >> 7;              // 128 blocks per batch
  const int row0 = (blockIdx.x & 127) * 64;
  const int gbase = b * NN + row0;

  if (t < 128) { sBase1[t] = base1[b * HH + t]; sP2[t] = P2[t]; }
  else         { sBaseP[t - 128] = baseP[b * HH + (t - 128)]; }
  for (int e = t; e < HH * KK; e += 256) {
    int h = e >> 3, kk = e & 7;
    sW2t[kk * 128 + h] = W2[e];               // transposed: conflict-free reads
  }
  if (t < 8) sB2[t] = b2[t];

  const int w = t >> 6, lane = t & 63, q = lane >> 4, ln = lane & 15;
  f4_t zero = {0.f, 0.f, 0.f, 0.f};
  f4_t acc1[8], accP[8];
#pragma unroll
  for (int i = 0; i < 8; ++i) { acc1[i] = zero; accP[i] = zero; }

  const int ar = t >> 2;                      // staging row 0..63
  const int ac = (t & 3) * 8;                 // staging col 0/8/16/24

  for (int kc = 0; kc < DD; kc += 32) {
    { // stage A: 64 rows x 32 dims, f32 -> bf16 inline
      const float4* src = (const float4*)(emb + (size_t)(gbase + ar) * DD + kc + ac);
      float4 f0 = src[0], f1 = src[1];
      union { unsigned short us[8]; uint4 v; } pk;
      pk.us[0] = f2bf(f0.x); pk.us[1] = f2bf(f0.y);
      pk.us[2] = f2bf(f0.z); pk.us[3] = f2bf(f0.w);
      pk.us[4] = f2bf(f1.x); pk.us[5] = f2bf(f1.y);
      pk.us[6] = f2bf(f1.z); pk.us[7] = f2bf(f1.w);
      *(uint4*)&sA[ar * 40 + ac] = pk.v;
    }
#pragma unroll
    for (int rep = 0; rep < 2; ++rep) {       // stage B tiles (pre-transposed bf16)
      int u = t + rep * 256;                  // 0..511 -> 128 rows x 4 x 16B
      int h = u >> 2, part = u & 3;
      *(uint4*)&sB1[h * 40 + part * 8] = *(const uint4*)(W1t + h * DD + kc + part * 8);
      *(uint4*)&sBP[h * 40 + part * 8] = *(const uint4*)(P1t + h * DD + kc + part * 8);
    }
    __syncthreads();
    bf8_t af = *(const bf8_t*)&sA[(w * 16 + ln) * 40 + q * 8];
#pragma unroll
    for (int ct = 0; ct < 8; ++ct) {
      bf8_t b1f = *(const bf8_t*)&sB1[(ct * 16 + ln) * 40 + q * 8];
      acc1[ct] = __builtin_amdgcn_mfma_f32_16x16x32_bf16(af, b1f, acc1[ct], 0, 0, 0);
      bf8_t bpf = *(const bf8_t*)&sBP[(ct * 16 + ln) * 40 + q * 8];
      accP[ct] = __builtin_amdgcn_mfma_f32_16x16x32_bf16(af, bpf, accP[ct], 0, 0, 0);
    }
    __syncthreads();
  }

  // Epilogue. C/D layout: col = lane&15, row = q*4 + reg.
  // A row's 128 cols live in one 16-lane group (8 col-tiles x 16 lanes).
  const float pb2v = pb2[0];
#pragma unroll
  for (int r = 0; r < 4; ++r) {
    const int grow = row0 + w * 16 + q * 4 + r;
    float s[8];
#pragma unroll
    for (int kk = 0; kk < 8; ++kk) s[kk] = 0.f;
    float ps = 0.f;
#pragma unroll
    for (int ct = 0; ct < 8; ++ct) {
      int col = ct * 16 + ln;
      float h1 = fmaxf(acc1[ct][r] + sBase1[col], 0.f);
      float hp = fmaxf(accP[ct][r] + sBaseP[col], 0.f);
#pragma unroll
      for (int kk = 0; kk < 8; ++kk) s[kk] = fmaf(h1, sW2t[kk * 128 + col], s[kk]);
      ps = fmaf(hp, sP2[col], ps);
    }
#pragma unroll
    for (int off = 1; off < 16; off <<= 1) {  // butterfly allreduce over 16 lanes
#pragma unroll
      for (int kk = 0; kk < 8; ++kk) s[kk] += __shfl_xor(s[kk], off, 64);
      ps += __shfl_xor(ps, off, 64);
    }
    if (ln == 0) {
      float path = 1.f / (1.f + __expf(-(ps + pb2v)));
      float scale = 1.f + path + (float)labels[b * NN + grow];
      float4 o0, o1;
      o0.x = (s[0] + sB2[0]) * scale; o0.y = (s[1] + sB2[1]) * scale;
      o0.z = (s[2] + sB2[2]) * scale; o0.w = (s[3] + sB2[3]) * scale;
      o1.x = (s[4] + sB2[4]) * scale; o1.y = (s[5] + sB2[5]) * scale;
      o1.z = (s[6] + sB2[6]) * scale; o1.w = (s[7] + sB2[7]) * scale;
      float4* dst = (float4*)(amps + (size_t)(b * NN + grow) * KK);
      dst[0] = o0; dst[1] = o1;
    }
  }
}

// ---------------------------------------------------------------------------
// Diffusion. Scale-invariance: per-step norms cancel; only final norm needed.
// ---------------------------------------------------------------------------
__device__ __forceinline__ void accum8(const float* __restrict__ src, int node,
                                       float4& a0, float4& a1) {
  const float4* p = (const float4*)(src + (size_t)node * KK);
  float4 v0 = p[0], v1 = p[1];
  a0.x += v0.x; a0.y += v0.y; a0.z += v0.z; a0.w += v0.w;
  a1.x += v1.x; a1.y += v1.y; a1.z += v1.z; a1.w += v1.w;
}

__device__ __forceinline__ void accum8m(const float* __restrict__ ain,
                                        const float* __restrict__ uin, int node,
                                        float4& a0, float4& a1) {
  const float4* pa = (const float4*)(ain + (size_t)node * KK);
  const float4* pu = (const float4*)(uin + (size_t)node * KK);
  float4 va0 = pa[0], va1 = pa[1], vu0 = pu[0], vu1 = pu[1];
  a0.x = fmaf(va0.x, vu0.x, a0.x); a0.y = fmaf(va0.y, vu0.y, a0.y);
  a0.z = fmaf(va0.z, vu0.z, a0.z); a0.w = fmaf(va0.w, vu0.w, a0.w);
  a1.x = fmaf(va1.x, vu1.x, a1.x); a1.y = fmaf(va1.y, vu1.y, a1.y);
  a1.z = fmaf(va1.z, vu1.z, a1.z); a1.w = fmaf(va1.w, vu1.w, a1.w);
}

__global__ __launch_bounds__(256) void sgather1(
    const int* __restrict__ nbr, const float* __restrict__ amps,
    float* __restrict__ uout)
{
  int idx = blockIdx.x * 256 + threadIdx.x;
  int base = idx & ~(NN - 1);
  const int4* nb = (const int4*)(nbr + (size_t)idx * DEG);
  float4 a0 = {0.f, 0.f, 0.f, 0.f}, a1 = {0.f, 0.f, 0.f, 0.f};
#pragma unroll
  for (int g = 0; g < 4; ++g) {
    int4 n = nb[g];
    accum8(amps, base + n.x, a0, a1);
    accum8(amps, base + n.y, a0, a1);
    accum8(amps, base + n.z, a0, a1);
    accum8(amps, base + n.w, a0, a1);
  }
  float4* dst = (float4*)(uout + (size_t)idx * KK);
  dst[0] = a0; dst[1] = a1;
}

__global__ __launch_bounds__(256) void sstep(
    const int* __restrict__ nbr, const float* __restrict__ amps,
    const float* __restrict__ uin, float* __restrict__ uout,
    float* __restrict__ normsq, int do_norm)
{
  int idx = blockIdx.x * 256 + threadIdx.x;
  int base = idx & ~(NN - 1);
  const int4* nb = (const int4*)(nbr + (size_t)idx * DEG);
  float4 a0 = {0.f, 0.f, 0.f, 0.f}, a1 = {0.f, 0.f, 0.f, 0.f};
#pragma unroll
  for (int g = 0; g < 4; ++g) {
    int4 n = nb[g];
    accum8m(amps, uin, base + n.x, a0, a1);
    accum8m(amps, uin, base + n.y, a0, a1);
    accum8m(amps, uin, base + n.z, a0, a1);
    accum8m(amps, uin, base + n.w, a0, a1);
  }
  float4* dst = (float4*)(uout + (size_t)idx * KK);
  dst[0] = a0; dst[1] = a1;
  if (do_norm) {
    float ss = a0.x * a0.x + a0.y * a0.y + a0.z * a0.z + a0.w * a0.w +
               a1.x * a1.x + a1.y * a1.y + a1.z * a1.z + a1.w * a1.w;
#pragma unroll
    for (int off = 1; off < 64; off <<= 1) ss += __shfl_xor(ss, off, 64);
    if ((threadIdx.x & 63) == 0) atomicAdd(&normsq[idx >> 13], ss);
  }
}

__global__ __launch_bounds__(256) void fout(
    const float* __restrict__ u, const float* __restrict__ normsq,
    float* __restrict__ out)
{
  int idx = blockIdx.x * 256 + threadIdx.x;
  float ns = normsq[idx >> 13];
  float inv = ns > 0.f ? rsqrtf(ns) : 1.f;
  const float4* p = (const float4*)(u + (size_t)idx * KK);
  float4 v0 = p[0], v1 = p[1];
  out[idx] = (fabsf(v0.x) + fabsf(v0.y) + fabsf(v0.z) + fabsf(v0.w) +
              fabsf(v1.x) + fabsf(v1.y) + fabsf(v1.z) + fabsf(v1.w)) * inv;
}

extern "C" void kernel_launch(void* const* d_in, const int* in_sizes, int n_in,
                              void* d_out, int out_size, void* d_ws, size_t ws_size,
                              hipStream_t stream) {
  const float* q   = (const float*)d_in[0];
  const float* emb = (const float*)d_in[1];
  const int*   nbr = (const int*)d_in[2];
  const int*   lab = (const int*)d_in[3];
  const float* W1  = (const float*)d_in[4];
  const float* b1  = (const float*)d_in[5];
  const float* W2  = (const float*)d_in[6];
  const float* b2  = (const float*)d_in[7];
  const float* P1  = (const float*)d_in[8];
  const float* pb1 = (const float*)d_in[9];
  const float* P2  = (const float*)d_in[10];
  const float* pb2 = (const float*)d_in[11];
  float* out = (float*)d_out;

  const size_t NK = (size_t)BB * NN * KK;     // 1,048,576 floats
  float* ws     = (float*)d_ws;
  float* amps   = ws;                         // 4 MB
  float* uA     = amps + NK;                  // 4 MB
  float* uB     = uA + NK;                    // 4 MB
  float* base1  = uB + NK;
  float* baseP  = base1 + BB * HH;
  float* normsq = baseP + BB * HH;            // 16 used, padded to 16 floats
  unsigned short* W1t = (unsigned short*)(normsq + 16);
  unsigned short* P1t = W1t + (size_t)HH * DD;

  kprep<<<48, 256, 0, stream>>>(q, W1, b1, P1, pb1, W1t, P1t, base1, baseP, normsq);
  kmlp<<<2048, 256, 0, stream>>>(emb, lab, W1t, P1t, base1, baseP, W2, b2, P2, pb2, amps);
  sgather1<<<512, 256, 0, stream>>>(nbr, amps, uA);
  sstep<<<512, 256, 0, stream>>>(nbr, amps, uA, uB, normsq, 0);
  sstep<<<512, 256, 0, stream>>>(nbr, amps, uB, uA, normsq, 1);
  fout<<<512, 256, 0, stream>>>(uA, normsq, out);
}

// Round 2
// 437.775 us; speedup vs baseline: 1.0997x; 1.0997x over previous
//
#include <hip/hip_runtime.h>
#include <cstdint>
#include <cstddef>

#define BB 16
#define NN 8192
#define DD 384
#define HH 128
#define KK 8
#define DEG 16

typedef short bf8_t __attribute__((ext_vector_type(8)));
typedef float f4_t __attribute__((ext_vector_type(4)));

__device__ __forceinline__ unsigned short f2bf(float f) {
  unsigned int u = __float_as_uint(f);
  u += 0x7FFFu + ((u >> 16) & 1u);   // RNE
  return (unsigned short)(u >> 16);
}

__device__ __forceinline__ bf8_t pack8(float4 f0, float4 f1) {
  union { unsigned short us[8]; bf8_t v; } pk;
  pk.us[0] = f2bf(f0.x); pk.us[1] = f2bf(f0.y);
  pk.us[2] = f2bf(f0.z); pk.us[3] = f2bf(f0.w);
  pk.us[4] = f2bf(f1.x); pk.us[5] = f2bf(f1.y);
  pk.us[6] = f2bf(f1.z); pk.us[7] = f2bf(f1.w);
  return pk.v;
}

// ---------------------------------------------------------------------------
// Kprep: (a) fold q@W[384:,:]+bias into per-batch base vectors, parallelized
// 32 blocks x (128 h x 2 d-halves) with 4 independent FMA chains;
// (b) transpose+convert W1[:384]/P1[:384] to bf16 [H][D]; (c) zero normsq.
// ---------------------------------------------------------------------------
__global__ __launch_bounds__(256) void kprep(
    const float* __restrict__ q, const float* __restrict__ W1,
    const float* __restrict__ b1, const float* __restrict__ P1,
    const float* __restrict__ pb1,
    unsigned short* __restrict__ W1t, unsigned short* __restrict__ P1t,
    float* __restrict__ base1, float* __restrict__ baseP,
    float* __restrict__ normsq)
{
  int blk = blockIdx.x, t = threadIdx.x;
  if (blk < 32) {
    int b = blk >> 1, net = blk & 1;
    const float* W = (net ? P1 : W1) + (size_t)DD * HH;   // q-half rows
    const float* qb = q + b * DD;
    int h = t & 127, half = t >> 7;
    int d0 = half * 192;
    float a0 = 0.f, a1 = 0.f, a2 = 0.f, a3 = 0.f;
    for (int d = d0; d < d0 + 192; d += 4) {
      a0 = fmaf(qb[d],     W[(size_t)d * HH + h],       a0);
      a1 = fmaf(qb[d + 1], W[(size_t)(d + 1) * HH + h], a1);
      a2 = fmaf(qb[d + 2], W[(size_t)(d + 2) * HH + h], a2);
      a3 = fmaf(qb[d + 3], W[(size_t)(d + 3) * HH + h], a3);
    }
    __shared__ float red[256];
    red[t] = (a0 + a1) + (a2 + a3);
    __syncthreads();
    if (t < 128) {
      float tot = red[t] + red[t + 128] + (net ? pb1[h] : b1[h]);
      (net ? baseP : base1)[b * HH + h] = tot;
    }
  } else {
    int e = (blk - 32) * 3072 + t;   // 32 blocks x 3072 = 2*49152 elems
    for (int it = 0; it < 12; ++it, e += 256) {
      int net = e / 49152;
      int r = e - net * 49152;
      int d = r >> 7;
      int h = r & 127;
      float v = (net ? P1 : W1)[d * HH + h];
      (net ? P1t : W1t)[h * DD + d] = f2bf(v);
    }
    if (blk == 32 && t < BB) normsq[t] = 0.f;
  }
}

// ---------------------------------------------------------------------------
// Kmlp: 64 rows x 128 cols x 2 nets per block. A-fragments loaded DIRECTLY
// from global (32B/lane, cacheline-coalesced) with 1-chunk register prefetch;
// only B (16 KB/chunk, L2-hot) staged in LDS with XOR part-swizzle for
// bank-uniform frag reads. 64 MFMA per barrier-pair (was 16).
// ---------------------------------------------------------------------------
__global__ __launch_bounds__(256, 4) void kmlp(
    const float* __restrict__ emb, const int* __restrict__ labels,
    const unsigned short* __restrict__ W1t, const unsigned short* __restrict__ P1t,
    const float* __restrict__ base1, const float* __restrict__ baseP,
    const float* __restrict__ W2, const float* __restrict__ b2,
    const float* __restrict__ P2, const float* __restrict__ pb2,
    float* __restrict__ amps)
{
  // [net][h][4 x 8 shorts], part p of row h stored at pos p ^ ((h>>1)&3):
  // frag read slot = (ln&1)*4 + (q ^ ((ln>>1)&3)) -> uniform over 8 slots.
  __shared__ __align__(16) unsigned short sB[2 * 4096];      // 16 KB
  __shared__ float sCol[128 * 4];                            // [col]{base1,baseP,P2,-}
  __shared__ float sW2a[128 * 9];                            // [col][kk], stride 9: conflict-free
  __shared__ float sB2[8];

  const int t = threadIdx.x;
  const int b = blockIdx.x >> 7;               // 128 blocks per batch
  const int row0 = (blockIdx.x & 127) * 64;

  if (t < 128) {
    sCol[t * 4 + 0] = base1[b * HH + t];
    sCol[t * 4 + 1] = baseP[b * HH + t];
    sCol[t * 4 + 2] = P2[t];
  }
  for (int e = t; e < HH * KK; e += 256) {
    int h = e >> 3, kk = e & 7;
    sW2a[h * 9 + kk] = W2[e];
  }
  if (t < 8) sB2[t] = b2[t];

  const int w = t >> 6, lane = t & 63, q = lane >> 4, ln = lane & 15;
  const float* arow = emb + (size_t)(b * NN + row0 + w * 16 + ln) * DD + q * 8;

  f4_t acc1[8], accP[8];
  f4_t zero = {0.f, 0.f, 0.f, 0.f};
#pragma unroll
  for (int i = 0; i < 8; ++i) { acc1[i] = zero; accP[i] = zero; }

  // ---- prologue: A chunk 0 + B chunk 0 ----
  float4 a0c = ((const float4*)arow)[0];
  float4 a1c = ((const float4*)arow)[1];
#pragma unroll
  for (int i = 0; i < 4; ++i) {
    int gidx = i * 256 + t;
    int net = gidx >> 9, rr = gidx & 511, h = rr >> 2, p = rr & 3;
    uint4 v = *(const uint4*)((net ? P1t : W1t) + h * DD + p * 8);
    int pos = p ^ ((h >> 1) & 3);
    *(uint4*)&sB[net * 4096 + h * 32 + pos * 8] = v;
  }

  for (int kc = 0;;) {
    __syncthreads();                            // B(kc) visible
    const int kn = kc + 32;
    float4 a0n, a1n;
    if (kn < DD) {                              // prefetch next A to regs
      a0n = ((const float4*)(arow + kn))[0];
      a1n = ((const float4*)(arow + kn))[1];
    }
    bf8_t af = pack8(a0c, a1c);
    const int swz = (q ^ ((ln >> 1) & 3)) * 8;
#pragma unroll
    for (int ct = 0; ct < 8; ++ct) {
      const int off = (ct * 16 + ln) * 32 + swz;
      bf8_t bf1 = *(const bf8_t*)&sB[off];
      acc1[ct] = __builtin_amdgcn_mfma_f32_16x16x32_bf16(af, bf1, acc1[ct], 0, 0, 0);
      bf8_t bfp = *(const bf8_t*)&sB[4096 + off];
      accP[ct] = __builtin_amdgcn_mfma_f32_16x16x32_bf16(af, bfp, accP[ct], 0, 0, 0);
    }
    kc = kn;
    if (kc >= DD) break;
    __syncthreads();                            // all reads of sB(kc-32) done
#pragma unroll
    for (int i = 0; i < 4; ++i) {
      int gidx = i * 256 + t;
      int net = gidx >> 9, rr = gidx & 511, h = rr >> 2, p = rr & 3;
      uint4 v = *(const uint4*)((net ? P1t : W1t) + h * DD + kc + p * 8);
      int pos = p ^ ((h >> 1) & 3);
      *(uint4*)&sB[net * 4096 + h * 32 + pos * 8] = v;
    }
    a0c = a0n; a1c = a1n;
  }

  // ---- epilogue: relu + second matmuls + sigmoid/label scaling ----
  const float pb2v = pb2[0];
#pragma unroll
  for (int r = 0; r < 4; ++r) {
    const int grow = row0 + w * 16 + q * 4 + r;
    float s[8];
#pragma unroll
    for (int kk = 0; kk < 8; ++kk) s[kk] = 0.f;
    float ps = 0.f;
#pragma unroll
    for (int ct = 0; ct < 8; ++ct) {
      int col = ct * 16 + ln;
      float h1 = fmaxf(acc1[ct][r] + sCol[col * 4 + 0], 0.f);
      float hp = fmaxf(accP[ct][r] + sCol[col * 4 + 1], 0.f);
#pragma unroll
      for (int kk = 0; kk < 8; ++kk) s[kk] = fmaf(h1, sW2a[col * 9 + kk], s[kk]);
      ps = fmaf(hp, sCol[col * 4 + 2], ps);
    }
#pragma unroll
    for (int off = 1; off < 16; off <<= 1) {
#pragma unroll
      for (int kk = 0; kk < 8; ++kk) s[kk] += __shfl_xor(s[kk], off, 64);
      ps += __shfl_xor(ps, off, 64);
    }
    if (ln == 0) {
      float path = 1.f / (1.f + __expf(-(ps + pb2v)));
      float scale = 1.f + path + (float)labels[b * NN + grow];
      float4 o0, o1;
      o0.x = (s[0] + sB2[0]) * scale; o0.y = (s[1] + sB2[1]) * scale;
      o0.z = (s[2] + sB2[2]) * scale; o0.w = (s[3] + sB2[3]) * scale;
      o1.x = (s[4] + sB2[4]) * scale; o1.y = (s[5] + sB2[5]) * scale;
      o1.z = (s[6] + sB2[6]) * scale; o1.w = (s[7] + sB2[7]) * scale;
      float4* dst = (float4*)(amps + (size_t)(b * NN + grow) * KK);
      dst[0] = o0; dst[1] = o1;
    }
  }
}

// ---------------------------------------------------------------------------
// Diffusion. Per-step norms cancel (uniform positive scalar); only final norm
// needed. The state*amps multiply is folded into the PRODUCER so gather loads
// are halved: u_m[i] = amps[i] * gather_sum(src[j]). 2 threads per node (K
// split 4+4) doubles wave-level parallelism.
// ---------------------------------------------------------------------------
__global__ __launch_bounds__(256) void sgm(
    const int* __restrict__ nbr, const float* __restrict__ src,
    const float* __restrict__ mult, float* __restrict__ out)
{
  int idx = blockIdx.x * 256 + threadIdx.x;     // 0..262143
  int node = idx >> 1;
  int off = (idx & 1) * 4;
  int base = node & ~(NN - 1);
  const int4* nb = (const int4*)(nbr + (size_t)node * DEG);
  float4 a = {0.f, 0.f, 0.f, 0.f};
#pragma unroll
  for (int g = 0; g < 4; ++g) {
    int4 n = nb[g];
    float4 v0 = *(const float4*)(src + (size_t)(base + n.x) * KK + off);
    float4 v1 = *(const float4*)(src + (size_t)(base + n.y) * KK + off);
    float4 v2 = *(const float4*)(src + (size_t)(base + n.z) * KK + off);
    float4 v3 = *(const float4*)(src + (size_t)(base + n.w) * KK + off);
    a.x += v0.x + v1.x + v2.x + v3.x;
    a.y += v0.y + v1.y + v2.y + v3.y;
    a.z += v0.z + v1.z + v2.z + v3.z;
    a.w += v0.w + v1.w + v2.w + v3.w;
  }
  float4 m = *(const float4*)(mult + (size_t)node * KK + off);
  a.x *= m.x; a.y *= m.y; a.z *= m.z; a.w *= m.w;
  *(float4*)(out + (size_t)node * KK + off) = a;
}

__global__ __launch_bounds__(256) void ss3(
    const int* __restrict__ nbr, const float* __restrict__ src,
    float* __restrict__ out, float* __restrict__ normsq)
{
  int idx = blockIdx.x * 256 + threadIdx.x;
  int node = idx >> 1;
  int off = (idx & 1) * 4;
  int base = node & ~(NN - 1);
  const int4* nb = (const int4*)(nbr + (size_t)node * DEG);
  float4 a = {0.f, 0.f, 0.f, 0.f};
#pragma unroll
  for (int g = 0; g < 4; ++g) {
    int4 n = nb[g];
    float4 v0 = *(const float4*)(src + (size_t)(base + n.x) * KK + off);
    float4 v1 = *(const float4*)(src + (size_t)(base + n.y) * KK + off);
    float4 v2 = *(const float4*)(src + (size_t)(base + n.z) * KK + off);
    float4 v3 = *(const float4*)(src + (size_t)(base + n.w) * KK + off);
    a.x += v0.x + v1.x + v2.x + v3.x;
    a.y += v0.y + v1.y + v2.y + v3.y;
    a.z += v0.z + v1.z + v2.z + v3.z;
    a.w += v0.w + v1.w + v2.w + v3.w;
  }
  *(float4*)(out + (size_t)node * KK + off) = a;
  float ss = a.x * a.x + a.y * a.y + a.z * a.z + a.w * a.w;
#pragma unroll
  for (int o = 1; o < 64; o <<= 1) ss += __shfl_xor(ss, o, 64);
  if ((threadIdx.x & 63) == 0) atomicAdd(&normsq[node >> 13], ss);
}

__global__ __launch_bounds__(256) void fout(
    const float* __restrict__ u, const float* __restrict__ normsq,
    float* __restrict__ out)
{
  int idx = blockIdx.x * 256 + threadIdx.x;
  float ns = normsq[idx >> 13];
  float inv = ns > 0.f ? rsqrtf(ns) : 1.f;
  const float4* p = (const float4*)(u + (size_t)idx * KK);
  float4 v0 = p[0], v1 = p[1];
  out[idx] = (fabsf(v0.x) + fabsf(v0.y) + fabsf(v0.z) + fabsf(v0.w) +
              fabsf(v1.x) + fabsf(v1.y) + fabsf(v1.z) + fabsf(v1.w)) * inv;
}

extern "C" void kernel_launch(void* const* d_in, const int* in_sizes, int n_in,
                              void* d_out, int out_size, void* d_ws, size_t ws_size,
                              hipStream_t stream) {
  const float* q   = (const float*)d_in[0];
  const float* emb = (const float*)d_in[1];
  const int*   nbr = (const int*)d_in[2];
  const int*   lab = (const int*)d_in[3];
  const float* W1  = (const float*)d_in[4];
  const float* b1  = (const float*)d_in[5];
  const float* W2  = (const float*)d_in[6];
  const float* b2  = (const float*)d_in[7];
  const float* P1  = (const float*)d_in[8];
  const float* pb1 = (const float*)d_in[9];
  const float* P2  = (const float*)d_in[10];
  const float* pb2 = (const float*)d_in[11];
  float* out = (float*)d_out;

  const size_t NK = (size_t)BB * NN * KK;     // 1,048,576 floats
  float* ws     = (float*)d_ws;
  float* amps   = ws;                         // 4 MB
  float* uB     = amps + NK;                  // 4 MB (u1m, later u3)
  float* uC     = uB + NK;                    // 4 MB (u2m)
  float* base1  = uC + NK;
  float* baseP  = base1 + BB * HH;
  float* normsq = baseP + BB * HH;
  unsigned short* W1t = (unsigned short*)(normsq + 16);
  unsigned short* P1t = W1t + (size_t)HH * DD;

  kprep<<<64, 256, 0, stream>>>(q, W1, b1, P1, pb1, W1t, P1t, base1, baseP, normsq);
  kmlp<<<2048, 256, 0, stream>>>(emb, lab, W1t, P1t, base1, baseP, W2, b2, P2, pb2, amps);
  sgm<<<1024, 256, 0, stream>>>(nbr, amps, amps, uB);   // u1m = amps ⊙ G(amps)
  sgm<<<1024, 256, 0, stream>>>(nbr, uB, amps, uC);     // u2m = amps ⊙ G(u1m)
  ss3<<<1024, 256, 0, stream>>>(nbr, uC, uB, normsq);   // u3  = G(u2m), ||.||
  fout<<<512, 256, 0, stream>>>(uB, normsq, out);
}